// Round 13
// baseline (171.522 us; speedup 1.0000x reference)
//
#include <hip/hip_runtime.h>
#include <hip/hip_bf16.h>

typedef __hip_bfloat16 bf16;
typedef __attribute__((ext_vector_type(8))) short short8v;   // bf16x8 MFMA fragment
typedef __attribute__((ext_vector_type(4))) float f32x4;     // MFMA accumulator

#define NJ   17
#define ND   128
#define NP   6
#define NH   4
#define NBT  16384
#define NG   2               // frames per block
#define NTOK (NG*NP)         // 12 tokens
#define NTHR 256             // 4 waves
#define GRID (NBT/NG)        // 8192 blocks
#define TSTR 136             // bf16 row stride: 272B
#define YSTR 132             // y fp32 row stride

// ws layout: bf16 wgt[81920] | fp32 bc[384] @163840 | u32 mb[16384] @165376
#define WS_WP 0
#define WS_WC 16384
#define WS_WO 65536
#define WS_BC 163840
#define WS_MB 165376

// LDS arena offsets (bytes); NTOK*TSTR*2 = 3264 per bf16 tile
#define OFF_POOL 0            // [12][136] bf16
#define OFF_TOKP 3264         // [12][136] bf16 (tok residual, bias included)
#define OFF_Q    6528         // [12][136] bf16 ; o overwrites q after PV
#define OFF_K    9792         // [12][136] bf16 ; dead after scores
#define OFF_V    13056        // [12][136] bf16 ; dead after PV  (ends 16320)
#define OFF_Y    9792         // [12][132] fp32 = 6336, aliases k|v (ends 16128)
#define OFF_PROB 16320        // [2][4][6][6] fp32 = 1152
#define ARENA_SZ 17472

__device__ __forceinline__ float bf2f(unsigned short u) {
    return __uint_as_float(((unsigned)u) << 16);
}
__device__ __forceinline__ f32x4 MFMA(short8v a, short8v b, f32x4 c) {
    return __builtin_amdgcn_mfma_f32_16x16x32_bf16(a, b, c, 0, 0, 0);
}
__device__ __forceinline__ short8v ldB(const bf16* __restrict__ W, int nt, int ks, int lane) {
    return *reinterpret_cast<const short8v*>(W + (nt*16 + (lane & 15))*ND + ks*32 + ((lane >> 4) << 3));
}
// A-fragment from [12][TSTR] LDS tile (single M-tile); rows >= 12 clamp in-bounds.
__device__ __forceinline__ short8v ldsA(const bf16* __restrict__ s, int ks, int lane) {
    int row = lane & 15;
    if (row >= NTOK) row = NTOK - 1;
    return *reinterpret_cast<const short8v*>(s + row*TSTR + ks*32 + ((lane >> 4) << 3));
}
// Block barrier with LDS ordering only — global loads stay in flight.
__device__ __forceinline__ void bsync() {
    asm volatile("s_waitcnt lgkmcnt(0)" ::: "memory");
    __builtin_amdgcn_s_barrier();
    asm volatile("" ::: "memory");
}
// Intra-wave LDS write->read fence (rule #18: sched_barrier after lgkmcnt).
#define WFENCE() do { \
    asm volatile("s_waitcnt lgkmcnt(0)" ::: "memory"); \
    __builtin_amdgcn_sched_barrier(0); \
} while (0)

// ---- fused prep (validated): Wp/Wo bf16 + Wc = Win@Wp + bc + mask bits ----
extern "C" __global__ __launch_bounds__(128)
void prep(const float* __restrict__ Wp, const float* __restrict__ Wi,
          const float* __restrict__ Wo, const float* __restrict__ bp,
          const float* __restrict__ bi, const float* __restrict__ mask,
          bf16* __restrict__ wgt, float* __restrict__ bc,
          unsigned* __restrict__ mbuf) {
    const int b = blockIdx.x, t = threadIdx.x;
    if (b < 384) {
        __shared__ float s_wi[128];
        __shared__ float s_red[128];
        s_wi[t] = Wi[b*128 + t];
        __syncthreads();
        float acc = 0.f;
        #pragma unroll 8
        for (int m = 0; m < 128; ++m)
            acc = fmaf(s_wi[m], Wp[m*128 + t], acc);
        wgt[WS_WC + b*128 + t] = __float2bfloat16(acc);
        s_red[t] = s_wi[t] * bp[t];
        __syncthreads();
        #pragma unroll
        for (int s = 64; s > 0; s >>= 1) {
            if (t < s) s_red[t] += s_red[t+s];
            __syncthreads();
        }
        if (t == 0) bc[b] = s_red[0] + bi[b];
    } else {
        int gid = (b - 384)*128 + t;          // 0..32767
        if (gid < 16384) wgt[WS_WP + gid] = __float2bfloat16(Wp[gid]);
        else             wgt[WS_WO + (gid - 16384)] = __float2bfloat16(Wo[gid - 16384]);
        if (gid < 16384) {
            const float* m = mask + (long)gid*NJ;
            unsigned bb = 0;
            #pragma unroll
            for (int j = 0; j < NJ; ++j)
                bb |= (m[j] > 0.05f) ? (1u << j) : 0u;
            mbuf[gid] = bb;
        }
    }
}

// Store rows < NTOK of a C column slice (1 M-tile) to a [12][TSTR] bf16 tile.
__device__ __forceinline__ void st12(bf16* __restrict__ dst, const f32x4 &a,
                                     float bv, int col, int lhi) {
    #pragma unroll
    for (int j = 0; j < 4; ++j) {
        int r = lhi*4 + j;
        if (r < NTOK) dst[r*TSTR + col] = __float2bfloat16(a[j] + bv);
    }
}

extern "C" __global__ __launch_bounds__(NTHR, 8)
void bpa_fused(const float* __restrict__ h_joint,
               const bf16* __restrict__ wgt, const float* __restrict__ bc,
               const unsigned* __restrict__ mbuf,
               const float* __restrict__ b_proj, const float* __restrict__ b_out,
               const float* __restrict__ ln_g,  const float* __restrict__ ln_b,
               float* __restrict__ out)
{
    __shared__ __align__(16) unsigned char s_arena[ARENA_SZ];
    bf16*  s_pool  = reinterpret_cast<bf16*>(s_arena + OFF_POOL);
    bf16*  s_tokp  = reinterpret_cast<bf16*>(s_arena + OFF_TOKP);
    bf16*  s_q     = reinterpret_cast<bf16*>(s_arena + OFF_Q);
    bf16*  s_k     = reinterpret_cast<bf16*>(s_arena + OFF_K);
    bf16*  s_v     = reinterpret_cast<bf16*>(s_arena + OFF_V);
    float* s_y     = reinterpret_cast<float*>(s_arena + OFF_Y);
    float* s_probs = reinterpret_cast<float*>(s_arena + OFF_PROB);

    const int tid  = threadIdx.x;
    const int lane = tid & 63;
    const int w    = tid >> 6;                          // wave 0..3
    const int l15  = lane & 15;
    const int lhi  = lane >> 4;                         // 0..3
    const long frame0 = (long)blockIdx.x * NG;

    // ---- Stage 1: pooling (thread = (frame f, col d)), unconditional loads ----
    {
        const int f = tid >> 7;                         // 0..1
        const int d = tid & (ND-1);
        const float* hcol = h_joint + (frame0 + f)*(long)(NJ*ND) + d;
        float hv[NJ];
        #pragma unroll
        for (int j = 0; j < NJ; ++j) hv[j] = hcol[j*ND];
        unsigned mb = mbuf[frame0 + f];
        #pragma unroll
        for (int j = 0; j < NJ; ++j)
            hv[j] = (mb >> j & 1) ? hv[j] : 0.f;
        float acc[NP];
        acc[0] = ((hv[0]+hv[1]) + (hv[2]+hv[3])) + hv[4];
        acc[1] = (hv[5]+hv[6]) + (hv[11]+hv[12]);
        acc[2] = hv[5]+hv[7]+hv[9];
        acc[3] = hv[6]+hv[8]+hv[10];
        acc[4] = hv[11]+hv[13]+hv[15];
        acc[5] = hv[12]+hv[14]+hv[16];
        const unsigned pm[NP] = {0x1Fu, 0x1860u, 0x2A0u, 0x540u, 0xA800u, 0x15000u};
        #pragma unroll
        for (int p = 0; p < NP; ++p) {
            float cnt = (float)__popc(mb & pm[p]);
            s_pool[(f*NP+p)*TSTR + d] = __float2bfloat16(acc[p] / fmaxf(cnt, 1e-6f));
        }
    }
    bsync();   // B1

    // ---- Stage 2: tok, q, k, v — wave w owns N-tiles {w, w+4} of each matrix.
    //      All outputs to LDS; nothing lives across the next barrier. ----
    #pragma unroll
    for (int t = 0; t < 4; ++t) {                       // 0=tok, 1=q, 2=k, 3=v
        bf16* dst = (t == 0) ? s_tokp : (t == 1) ? s_q : (t == 2) ? s_k : s_v;
        const bf16* W = (t == 0) ? (wgt + WS_WP) : (wgt + WS_WC);
        #pragma unroll
        for (int i = 0; i < 2; ++i) {
            int ntl = w + i*4;                          // local N-tile 0..7
            int nt  = (t == 0) ? ntl : (t-1)*8 + ntl;   // row block in W
            short8v b[4];
            #pragma unroll
            for (int ks = 0; ks < 4; ++ks) b[ks] = ldB(W, nt, ks, lane);
            f32x4 acc = (f32x4)(0.f);
            #pragma unroll
            for (int ks = 0; ks < 4; ++ks)
                acc = MFMA(ldsA(s_pool, ks, lane), b[ks], acc);
            int col = ntl*16 + l15;
            float bv = (t == 0) ? b_proj[col] : bc[nt*16 + l15];
            st12(dst, acc, bv, col, lhi);
        }
    }
    bsync();   // B2

    // ---- Stage 3 (all 4 waves): wave = (frame fq = w&1, head-pair hsel = w>>1).
    //      MFMA scores + wave-parallel softmax + PV; intra-wave WFENCE only. ----
    {
        const int fq   = w & 1;
        const int hsel = w >> 1;
        float* s_pr = s_probs + fq*(NH*NP*NP);
        const int arow = (fq*NP + (l15 > 5 ? 5 : l15))*TSTR + (lhi << 3);
        #pragma unroll
        for (int hh = 0; hh < 2; ++hh) {
            const int h = hsel*2 + hh;
            short8v qa = *reinterpret_cast<const short8v*>(s_q + arow + h*32);
            short8v kb = *reinterpret_cast<const short8v*>(s_k + arow + h*32);
            f32x4 c = MFMA(qa, kb, (f32x4)(0.f));
            #pragma unroll
            for (int j = 0; j < 4; ++j) {
                int q = lhi*4 + j;
                float sc  = c[j] * 0.17677669529663688f;     // 1/sqrt(32)
                float scm = (l15 < NP) ? sc : -1e30f;
                scm = fmaxf(scm, __shfl_xor(scm, 1));
                scm = fmaxf(scm, __shfl_xor(scm, 2));
                scm = fmaxf(scm, __shfl_xor(scm, 4));
                scm = fmaxf(scm, __shfl_xor(scm, 8));
                float e = (l15 < NP) ? __expf(sc - scm) : 0.f;
                float den = e;
                den += __shfl_xor(den, 1);
                den += __shfl_xor(den, 2);
                den += __shfl_xor(den, 4);
                den += __shfl_xor(den, 8);
                if (q < NP && l15 < NP)
                    s_pr[(h*NP + q)*NP + l15] = e / den;
            }
        }
        WFENCE();   // own-head P visible within wave
        // PV: lane owns col c = 64*hsel + lane; head h = hsel*2 + (lane>>5).
        {
            const int c = hsel*64 + lane;
            const int h = hsel*2 + (lane >> 5);
            const float* pr = s_pr + h*NP*NP;
            float vv[NP];
            #pragma unroll
            for (int pk = 0; pk < NP; ++pk)
                vv[pk] = bf2f(*reinterpret_cast<const unsigned short*>(&s_v[(fq*NP+pk)*TSTR + c]));
            #pragma unroll
            for (int qi = 0; qi < NP; ++qi) {
                const float* pq = pr + qi*NP;
                float o = pq[0]*vv[0]+pq[1]*vv[1]+pq[2]*vv[2]
                        + pq[3]*vv[3]+pq[4]*vv[4]+pq[5]*vv[5];
                s_q[(fq*NP+qi)*TSTR + c] = __float2bfloat16(o);   // o over dead q cols
            }
        }
    }
    bsync();   // B3

    // ---- part_importance (12 threads) + Stage 4: y = o@Wo^T + b_out + tok ----
    if (tid < NG*NP) {
        int f = tid / NP, pk = tid - f*NP;
        const float* pr = s_probs + f*(NH*NP*NP);
        float s = 0.f;
        #pragma unroll
        for (int h = 0; h < NH; ++h)
            #pragma unroll
            for (int q = 0; q < NP; ++q)
                s += pr[(h*NP+q)*NP + pk];
        out[(long)NBT*NP*ND + (frame0+f)*NP + pk] = s * (1.f/24.f);
    }
    #pragma unroll
    for (int i = 0; i < 2; ++i) {                       // wave w owns N-tiles {w, w+4}
        int nt = w + i*4;
        short8v bo[4];
        #pragma unroll
        for (int ks = 0; ks < 4; ++ks) bo[ks] = ldB(wgt + WS_WO, nt, ks, lane);
        f32x4 acc = (f32x4)(0.f);
        #pragma unroll
        for (int ks = 0; ks < 4; ++ks)
            acc = MFMA(ldsA(s_q, ks, lane), bo[ks], acc);
        int col = nt*16 + l15;
        float bv = b_out[col];
        #pragma unroll
        for (int j = 0; j < 4; ++j) {
            int r = lhi*4 + j;
            if (r < NTOK) {
                float resid = bf2f(*reinterpret_cast<const unsigned short*>(&s_tokp[r*TSTR + col]));
                s_y[r*YSTR + col] = acc[j] + bv + resid;
            }
        }
    }
    bsync();   // B4

    // ---- Stage 5: fused LayerNorm + store (wave w owns tokens 3w..3w+2) ----
    {
        const int c0 = lane*2;
        float2 g2 = *reinterpret_cast<const float2*>(ln_g + c0);
        float2 b2 = *reinterpret_cast<const float2*>(ln_b + c0);
        #pragma unroll
        for (int ti = 0; ti < 3; ++ti) {
            int token = w*3 + ti;
            float2 v = *reinterpret_cast<const float2*>(s_y + token*YSTR + c0);
            float s  = v.x + v.y;
            float s2 = v.x*v.x + v.y*v.y;
            s  += __shfl_xor(s, 1);  s  += __shfl_xor(s, 2);
            s  += __shfl_xor(s, 4);  s  += __shfl_xor(s, 8);
            s  += __shfl_xor(s, 16); s  += __shfl_xor(s, 32);
            s2 += __shfl_xor(s2, 1); s2 += __shfl_xor(s2, 2);
            s2 += __shfl_xor(s2, 4); s2 += __shfl_xor(s2, 8);
            s2 += __shfl_xor(s2, 16); s2 += __shfl_xor(s2, 32);
            float mean = s * (1.f/128.f);
            float rinv = rsqrtf(s2 * (1.f/128.f) - mean*mean + 1e-5f);
            float2 r;
            r.x = (v.x - mean)*rinv*g2.x + b2.x;
            r.y = (v.y - mean)*rinv*g2.y + b2.y;
            *reinterpret_cast<float2*>(out + (frame0*NP + token)*(long)ND + c0) = r;
        }
    }
}

extern "C" void kernel_launch(void* const* d_in, const int* in_sizes, int n_in,
                              void* d_out, int out_size, void* d_ws, size_t ws_size,
                              hipStream_t stream) {
    const float* h_joint = (const float*)d_in[0];
    const float* mask    = (const float*)d_in[1];
    const float* W_proj  = (const float*)d_in[2];
    const float* b_proj  = (const float*)d_in[3];
    const float* W_in    = (const float*)d_in[4];
    const float* b_in    = (const float*)d_in[5];
    const float* W_out   = (const float*)d_in[6];
    const float* b_out   = (const float*)d_in[7];
    const float* ln_g    = (const float*)d_in[8];
    const float* ln_b    = (const float*)d_in[9];
    float* out = (float*)d_out;
    bf16*     wgt  = (bf16*)d_ws;
    float*    bc   = (float*)((char*)d_ws + WS_BC);
    unsigned* mbuf = (unsigned*)((char*)d_ws + WS_MB);

    hipLaunchKernelGGL(prep, dim3(640), dim3(128), 0, stream,
                       W_proj, W_in, W_out, b_proj, b_in, mask, wgt, bc, mbuf);
    hipLaunchKernelGGL(bpa_fused, dim3(GRID), dim3(NTHR), 0, stream,
                       h_joint, wgt, bc, mbuf, b_proj, b_out, ln_g, ln_b, out);
}